// Round 10
// baseline (143.702 us; speedup 1.0000x reference)
//
#include <hip/hip_runtime.h>
#include <hip/hip_bf16.h>
#include <math.h>

// Problem shapes (fixed by setup_inputs)
#define B_  2
#define Q_  100
#define G_  10
#define T_  5
#define H_  128
#define W_  128
#define C_  41
#define HW_ (H_*W_)

// acc layout per (b,q): [rowsum_tot, colsum_tot, then per g: Sfgy, Sfully, Sfgx, Sfullx]
#define ACC_STRIDE (2 + G_*4)

__device__ __forceinline__ float sigmoidf_(float x) {
    return 1.0f / (1.0f + expf(-x));
}

// ---------------------------------------------------------------------------
// Kernel 1: bounding boxes from box_masks. One block per (b,g,t).
// Matches _bounds(): first-true idx, last-true idx+1; (0,0) when empty.
// ---------------------------------------------------------------------------
__global__ void box_kernel(const float* __restrict__ bm, int4* __restrict__ boxes) {
    int bx = blockIdx.x;                      // (b*G+g)*T + t
    const float4* src4 = (const float4*)(bm + (size_t)bx * HW_);
    int tid = threadIdx.x;

    int minh = H_, maxh = -1, minw = W_, maxw = -1;
    for (int i = tid; i < HW_/4; i += 256) {
        float4 v = src4[i];
        int h = i >> 5;            // (i*4)/128
        int wb = (i & 31) << 2;
        if (v.x > 0.5f) { minh = min(minh,h); maxh = max(maxh,h); minw = min(minw,wb+0); maxw = max(maxw,wb+0); }
        if (v.y > 0.5f) { minh = min(minh,h); maxh = max(maxh,h); minw = min(minw,wb+1); maxw = max(maxw,wb+1); }
        if (v.z > 0.5f) { minh = min(minh,h); maxh = max(maxh,h); minw = min(minw,wb+2); maxw = max(maxw,wb+2); }
        if (v.w > 0.5f) { minh = min(minh,h); maxh = max(maxh,h); minw = min(minw,wb+3); maxw = max(maxw,wb+3); }
    }
    for (int o = 32; o; o >>= 1) {
        minh = min(minh, __shfl_down(minh, o));
        maxh = max(maxh, __shfl_down(maxh, o));
        minw = min(minw, __shfl_down(minw, o));
        maxw = max(maxw, __shfl_down(maxw, o));
    }
    __shared__ int red[4][4];
    int wid = tid >> 6;
    if ((tid & 63) == 0) { red[wid][0]=minh; red[wid][1]=maxh; red[wid][2]=minw; red[wid][3]=maxw; }
    __syncthreads();
    if (tid == 0) {
        for (int i = 1; i < 4; ++i) {
            minh = min(minh, red[i][0]); maxh = max(maxh, red[i][1]);
            minw = min(minw, red[i][2]); maxw = max(maxw, red[i][3]);
        }
        int4 r;
        if (maxh < 0) r = make_int4(0,0,0,0);
        else          r = make_int4(minh, maxh+1, minw, maxw+1);
        boxes[bx] = r;
    }
}

// ---------------------------------------------------------------------------
// Kernel 2: main tile kernel. One block per (b,q,t); 256 threads.
// LDS holds the RAW tile (sigmoid deferred past the maxes — monotonic &
// strictly positive, so in-box maxes commute with sigmoid), XOR-swizzled on
// float4 quads:
//   element (h,w) lives at s[h*128 + (((w>>2) ^ (h&31))<<2) + (w&3)]
// -> row-direction b128 reads and col-direction b32 reads both balanced
//    across the 32 banks.
// ---------------------------------------------------------------------------
__global__ __launch_bounds__(256, 2) void tile_kernel(const float* __restrict__ masks,
                                                      const int4*  __restrict__ boxes,
                                                      float*       __restrict__ acc) {
    __shared__ float4 s4[HW_/4];              // 64 KiB, raw logits, swizzled
    __shared__ float s_rowsig[H_];            // sigmoid(rowmax)
    __shared__ float s_colsig[W_];            // sigmoid(colmax)
    float* s = (float*)s4;

    int bx = blockIdx.x;
    int t  = bx % T_;
    int q  = (bx / T_) % Q_;
    int b  = bx / (T_ * Q_);
    int tid = threadIdx.x;

    const float4* src4 = (const float4*)(masks + ((size_t)(b*Q_ + q)*T_ + t) * HW_);

    // Phase 1: load raw, swizzled store (no sigmoid here)
    #pragma unroll
    for (int k = 0; k < 16; ++k) {
        int i = tid + k*256;
        float4 v = src4[i];
        int h = i >> 5;
        int j = i & 31;
        s4[h*32 + (j ^ (h & 31))] = v;
    }
    __syncthreads();

    // Phase 2: full row / col maxima. Waves 0-1: rows (b128). Waves 2-3: cols
    // (b128 over 4 cols at once, 4-way h-split + shfl reduce).
    if (tid < 128) {
        int h = tid;
        const float4* row = s4 + h*32;
        float m = -INFINITY;
        #pragma unroll 8
        for (int j = 0; j < 32; ++j) {
            float4 v = row[j ^ (h & 31)];
            m = fmaxf(m, fmaxf(fmaxf(v.x, v.y), fmaxf(v.z, v.w)));
        }
        s_rowsig[h] = sigmoidf_(m);
    } else {
        int t2 = tid - 128;
        int jq = t2 >> 2, part = t2 & 3;      // quad-col 0..31, h-segment 0..3
        float4 mm = make_float4(-INFINITY,-INFINITY,-INFINITY,-INFINITY);
        #pragma unroll 8
        for (int i = 0; i < 32; ++i) {
            int h = part*32 + i;
            float4 v = s4[h*32 + (jq ^ (h & 31))];
            mm.x = fmaxf(mm.x, v.x); mm.y = fmaxf(mm.y, v.y);
            mm.z = fmaxf(mm.z, v.z); mm.w = fmaxf(mm.w, v.w);
        }
        mm.x = fmaxf(mm.x, __shfl_xor(mm.x, 1)); mm.x = fmaxf(mm.x, __shfl_xor(mm.x, 2));
        mm.y = fmaxf(mm.y, __shfl_xor(mm.y, 1)); mm.y = fmaxf(mm.y, __shfl_xor(mm.y, 2));
        mm.z = fmaxf(mm.z, __shfl_xor(mm.z, 1)); mm.z = fmaxf(mm.z, __shfl_xor(mm.z, 2));
        mm.w = fmaxf(mm.w, __shfl_xor(mm.w, 1)); mm.w = fmaxf(mm.w, __shfl_xor(mm.w, 2));
        float cm = (part == 0) ? mm.x : (part == 1) ? mm.y : (part == 2) ? mm.z : mm.w;
        s_colsig[t2] = sigmoidf_(cm);         // col index = jq*4 + part = t2
    }
    __syncthreads();

    float* accq = acc + (size_t)(b*Q_ + q) * ACC_STRIDE;

    // rowsum_tot / colsum_tot
    {
        float v = (tid < 128) ? s_rowsig[tid] : s_colsig[tid - 128];
        for (int o = 32; o; o >>= 1) v += __shfl_down(v, o);
        if ((tid & 63) == 0) atomicAdd(accq + (tid >> 7), v);   // waves 0,1 -> slot0; 2,3 -> slot1
    }

    // Per-target box stats: one wave per (g, axis). Waves 0/1: rows of even/odd
    // g; waves 2/3: cols of even/odd g. Box bounds are wave-uniform.
    float* accg = accq + 2;
    int wid = tid >> 6, lane = tid & 63;
    const int4* boxbt = boxes + (b*G_)*T_ + t;
    #pragma unroll
    for (int gi = 0; gi < 5; ++gi) {
        int g = (wid & 1) + gi*2;
        int4 bb = boxbt[g*T_];
        int y0 = bb.x, y1 = bb.y, x0 = bb.z, x1 = bb.w;
        float fg = 0.0f, full = 0.0f;
        if (wid < 2) {
            int j0 = x0 >> 2, j1e = (x1 + 3) >> 2;
            for (int h = y0 + lane; h < y1; h += 64) {
                float m = -INFINITY;
                for (int j = j0; j < j1e; ++j) {
                    float4 v = s4[h*32 + (j ^ (h & 31))];
                    if (j == j0 || j == j1e - 1) {     // wave-uniform edge mask
                        int wb = j << 2;
                        v.x = (wb+0 >= x0 && wb+0 < x1) ? v.x : -INFINITY;
                        v.y = (wb+1 >= x0 && wb+1 < x1) ? v.y : -INFINITY;
                        v.z = (wb+2 >= x0 && wb+2 < x1) ? v.z : -INFINITY;
                        v.w = (wb+3 >= x0 && wb+3 < x1) ? v.w : -INFINITY;
                    }
                    m = fmaxf(m, fmaxf(fmaxf(v.x, v.y), fmaxf(v.z, v.w)));
                }
                fg   += sigmoidf_(m);
                full += s_rowsig[h];
            }
        } else {
            for (int w = x0 + lane; w < x1; w += 64) {
                int j = w >> 2, r = w & 3;
                float m = -INFINITY;
                for (int h = y0; h < y1; ++h)
                    m = fmaxf(m, s[h*128 + ((j ^ (h & 31)) << 2) + r]);
                fg   += sigmoidf_(m);
                full += s_colsig[w];
            }
        }
        for (int o = 32; o; o >>= 1) {
            fg   += __shfl_down(fg, o);
            full += __shfl_down(full, o);
        }
        if (lane == 0) {
            int base = (wid < 2) ? 0 : 2;
            atomicAdd(accg + g*4 + base + 0, fg);
            atomicAdd(accg + g*4 + base + 1, full);
        }
    }
}

// ---------------------------------------------------------------------------
// Kernel 3: finalize. One block (64 threads) per (b,q).
// ---------------------------------------------------------------------------
__global__ void final_kernel(const float* __restrict__ logits,
                             const int*   __restrict__ tgt_ids,
                             const int4*  __restrict__ boxes,
                             const float* __restrict__ acc,
                             float*       __restrict__ out) {
    int bq = blockIdx.x;
    int b  = bq / Q_;
    int tid = threadIdx.x;

    __shared__ float s_p[C_];
    float x = (tid < C_) ? logits[(size_t)bq*C_ + tid] : -INFINITY;
    float mx = x;
    for (int o = 32; o; o >>= 1) mx = fmaxf(mx, __shfl_xor(mx, o));
    float e = (tid < C_) ? expf(x - mx) : 0.0f;
    float sum = e;
    for (int o = 32; o; o >>= 1) sum += __shfl_xor(sum, o);
    if (tid < C_) s_p[tid] = e / sum;
    __syncthreads();

    if (tid < G_) {
        int g = tid;
        int id = tgt_ids[b*G_ + g];
        float cls = -s_p[id];

        const float* a  = acc + (size_t)bq * ACC_STRIDE;
        float rowsum_tot = a[0];
        float colsum_tot = a[1];
        const float* ag = a + 2 + g*4;
        float Sfgy = ag[0], Sfully = ag[1], Sfgx = ag[2], Sfullx = ag[3];

        int Ty = 0, Tx = 0;
        #pragma unroll
        for (int t = 0; t < T_; ++t) {
            int4 bb = boxes[(b*G_ + g)*T_ + t];
            Ty += bb.y - bb.x;
            Tx += bb.w - bb.z;
        }

        float psum_y = Sfgy + (rowsum_tot - Sfully);
        float dice_y = 1.0f - (2.0f*Sfgy + 1.0f) / (psum_y + (float)Ty + 1.0f);
        float psum_x = Sfgx + (colsum_tot - Sfullx);
        float dice_x = 1.0f - (2.0f*Sfgx + 1.0f) / (psum_x + (float)Tx + 1.0f);

        out[(size_t)bq*G_ + g] = 2.0f*cls + 5.0f*(dice_y + dice_x);
    }
}

// ---------------------------------------------------------------------------
extern "C" void kernel_launch(void* const* d_in, const int* in_sizes, int n_in,
                              void* d_out, int out_size, void* d_ws, size_t ws_size,
                              hipStream_t stream) {
    const float* pred_logits = (const float*)d_in[0];   // (B,Q,C)
    const float* pred_masks  = (const float*)d_in[1];   // (B,Q,T,H,W)
    const float* box_masks   = (const float*)d_in[2];   // (B,G,T,H,W)
    const int*   tgt_ids     = (const int*)d_in[3];     // (B,G)
    float* out = (float*)d_out;                         // (B,Q,G)

    char* ws = (char*)d_ws;
    int4*  boxes = (int4*)ws;                            // B*G*T int4 = 1600 B
    float* acc   = (float*)(ws + 2048);                  // B*Q*ACC_STRIDE floats

    // zero the accumulators (ws is poisoned each launch)
    hipMemsetAsync(acc, 0, (size_t)B_*Q_*ACC_STRIDE*sizeof(float), stream);

    box_kernel<<<B_*G_*T_, 256, 0, stream>>>(box_masks, boxes);
    tile_kernel<<<B_*Q_*T_, 256, 0, stream>>>(pred_masks, boxes, acc);
    final_kernel<<<B_*Q_, 64, 0, stream>>>(pred_logits, tgt_ids, boxes, acc, out);
}